// Round 1
// baseline (1533.994 us; speedup 1.0000x reference)
//
#include <hip/hip_runtime.h>

#define N_NODESC 100000
#define N_EDGESC 1600000
#define BN_EPSC 1e-5f

// ---------------------------------------------------------------------------
// K1: per-edge message + scatter-add.  16 threads per edge, float4 each.
// grid = E*16/256 = 100000 blocks exactly.
// ---------------------------------------------------------------------------
__global__ __launch_bounds__(256) void k_scatter(
    const float* __restrict__ x, const float* __restrict__ emb,
    const int* __restrict__ ei, const int* __restrict__ ea,
    float* __restrict__ agg)
{
    const int gid = blockIdx.x * 256 + threadIdx.x;
    const int e = gid >> 4;
    const int q = gid & 15;
    const int src = ei[e];
    const int dst = ei[N_EDGESC + e];
    const int a = ea[e];
    const float4 xv = ((const float4*)x)[(size_t)src * 16 + q];
    const float4 tv = ((const float4*)emb)[a * 16 + q];
    float4 m;
    m.x = fmaxf(xv.x + tv.x, 0.0f);
    m.y = fmaxf(xv.y + tv.y, 0.0f);
    m.z = fmaxf(xv.z + tv.z, 0.0f);
    m.w = fmaxf(xv.w + tv.w, 0.0f);
    float* p = agg + (size_t)dst * 64 + q * 4;
    unsafeAtomicAdd(p + 0, m.x);
    unsafeAtomicAdd(p + 1, m.y);
    unsafeAtomicAdd(p + 2, m.z);
    unsafeAtomicAdd(p + 3, m.w);
}

// ---------------------------------------------------------------------------
// K2: h1 = ((1+eps)*x + agg) @ W1 + b1 ; also accumulate BN column sums.
// 64 nodes per block, 256 threads: thread = (node r = t/4, colgroup g = t%4).
// ---------------------------------------------------------------------------
__global__ __launch_bounds__(256) void k_mlp1(
    const float* __restrict__ x, const float* __restrict__ agg,
    const float* __restrict__ W1, const float* __restrict__ b1,
    const float* __restrict__ epsp,
    float* __restrict__ h1, float* __restrict__ cs, float* __restrict__ css)
{
    __shared__ float lin[64][68];   // +4 pad: 2-way bank alias only (free)
    __shared__ float lW[4096];
    __shared__ float redS[4][64];
    __shared__ float redQ[4][64];
    const int t = threadIdx.x;
    const int nbase = blockIdx.x * 64;
    const float sc1 = 1.0f + epsp[0];

    {   // stage W1 (64x64) into LDS, coalesced float4
        const float4* W4 = (const float4*)W1;
        float4* lW4 = (float4*)lW;
        #pragma unroll
        for (int i = 0; i < 4; i++) lW4[i * 256 + t] = W4[i * 256 + t];
    }
    {   // stage 64 input rows: (1+eps)*x + agg
        const float4* x4 = (const float4*)x;
        const float4* a4 = (const float4*)agg;
        #pragma unroll
        for (int i = 0; i < 4; i++) {
            const int ln = i * 16 + (t >> 4);
            const int q = t & 15;
            const int n = nbase + ln;
            float4 v = make_float4(0.f, 0.f, 0.f, 0.f);
            if (n < N_NODESC) {
                const float4 xv = x4[(size_t)n * 16 + q];
                const float4 av = a4[(size_t)n * 16 + q];
                v.x = fmaf(sc1, xv.x, av.x);
                v.y = fmaf(sc1, xv.y, av.y);
                v.z = fmaf(sc1, xv.z, av.z);
                v.w = fmaf(sc1, xv.w, av.w);
            }
            *(float4*)&lin[ln][q * 4] = v;
        }
    }
    __syncthreads();

    const int r = t >> 2;
    const int g = t & 3;
    const int n = nbase + r;
    const float4* lW4 = (const float4*)lW;
    const float4* b4 = (const float4*)b1;
    float4 acc0 = b4[g * 4 + 0];
    float4 acc1 = b4[g * 4 + 1];
    float4 acc2 = b4[g * 4 + 2];
    float4 acc3 = b4[g * 4 + 3];
    for (int k = 0; k < 64; k++) {
        const float a = lin[r][k];
        const float4 w0 = lW4[k * 16 + g * 4 + 0];
        const float4 w1 = lW4[k * 16 + g * 4 + 1];
        const float4 w2 = lW4[k * 16 + g * 4 + 2];
        const float4 w3 = lW4[k * 16 + g * 4 + 3];
        acc0.x = fmaf(a, w0.x, acc0.x); acc0.y = fmaf(a, w0.y, acc0.y);
        acc0.z = fmaf(a, w0.z, acc0.z); acc0.w = fmaf(a, w0.w, acc0.w);
        acc1.x = fmaf(a, w1.x, acc1.x); acc1.y = fmaf(a, w1.y, acc1.y);
        acc1.z = fmaf(a, w1.z, acc1.z); acc1.w = fmaf(a, w1.w, acc1.w);
        acc2.x = fmaf(a, w2.x, acc2.x); acc2.y = fmaf(a, w2.y, acc2.y);
        acc2.z = fmaf(a, w2.z, acc2.z); acc2.w = fmaf(a, w2.w, acc2.w);
        acc3.x = fmaf(a, w3.x, acc3.x); acc3.y = fmaf(a, w3.y, acc3.y);
        acc3.z = fmaf(a, w3.z, acc3.z); acc3.w = fmaf(a, w3.w, acc3.w);
    }
    if (n < N_NODESC) {
        float4* h4 = (float4*)h1;
        h4[(size_t)n * 16 + g * 4 + 0] = acc0;
        h4[(size_t)n * 16 + g * 4 + 1] = acc1;
        h4[(size_t)n * 16 + g * 4 + 2] = acc2;
        h4[(size_t)n * 16 + g * 4 + 3] = acc3;
    }

    // --- BN partial stats: reduce over the 16 rows in each wave via shfl ---
    float vs[16], vq[16];
    const float msk = (n < N_NODESC) ? 1.0f : 0.0f;
    {
        const float a0[16] = {acc0.x, acc0.y, acc0.z, acc0.w,
                              acc1.x, acc1.y, acc1.z, acc1.w,
                              acc2.x, acc2.y, acc2.z, acc2.w,
                              acc3.x, acc3.y, acc3.z, acc3.w};
        #pragma unroll
        for (int i = 0; i < 16; i++) {
            const float v = a0[i] * msk;
            vs[i] = v;
            vq[i] = v * a0[i];
        }
    }
    #pragma unroll
    for (int off = 4; off < 64; off <<= 1) {
        #pragma unroll
        for (int i = 0; i < 16; i++) {
            vs[i] += __shfl_xor(vs[i], off);
            vq[i] += __shfl_xor(vq[i], off);
        }
    }
    const int lane = t & 63;
    const int w = t >> 6;
    if (lane < 4) {
        #pragma unroll
        for (int i = 0; i < 16; i++) {
            redS[w][lane * 16 + i] = vs[i];
            redQ[w][lane * 16 + i] = vq[i];
        }
    }
    __syncthreads();
    if (t < 64) {
        const float s = redS[0][t] + redS[1][t] + redS[2][t] + redS[3][t];
        const float qq = redQ[0][t] + redQ[1][t] + redQ[2][t] + redQ[3][t];
        unsafeAtomicAdd(&cs[t], s);
        unsafeAtomicAdd(&css[t], qq);
    }
}

// ---------------------------------------------------------------------------
// K3: out = relu(BN(h1)) @ W2 + b2.  h1 aliases d_out: each block stages its
// 64 rows into LDS (barrier) before overwriting them.
// ---------------------------------------------------------------------------
__global__ __launch_bounds__(256) void k_mlp2(
    const float* h1, const float* __restrict__ W2, const float* __restrict__ b2,
    const float* __restrict__ gamma, const float* __restrict__ beta,
    const float* __restrict__ cs, const float* __restrict__ css,
    float* out)
{
    __shared__ float lin[64][68];
    __shared__ float lW[4096];
    __shared__ float scl[64];
    __shared__ float sft[64];
    const int t = threadIdx.x;
    const int nbase = blockIdx.x * 64;

    if (t < 64) {
        const float inv = 1.0f / (float)N_NODESC;
        const float mu = cs[t] * inv;
        const float var = css[t] * inv - mu * mu;
        const float rs = rsqrtf(var + BN_EPSC);
        const float s = rs * gamma[t];
        scl[t] = s;
        sft[t] = fmaf(-mu, s, beta[t]);
    }
    {
        const float4* W4 = (const float4*)W2;
        float4* lW4 = (float4*)lW;
        #pragma unroll
        for (int i = 0; i < 4; i++) lW4[i * 256 + t] = W4[i * 256 + t];
    }
    __syncthreads();   // scl/sft ready
    {
        const float4* h4 = (const float4*)h1;
        #pragma unroll
        for (int i = 0; i < 4; i++) {
            const int ln = i * 16 + (t >> 4);
            const int q = t & 15;
            const int n = nbase + ln;
            float4 v = make_float4(0.f, 0.f, 0.f, 0.f);
            if (n < N_NODESC) {
                const float4 h = h4[(size_t)n * 16 + q];
                const int c = q * 4;
                v.x = fmaxf(fmaf(h.x, scl[c + 0], sft[c + 0]), 0.f);
                v.y = fmaxf(fmaf(h.y, scl[c + 1], sft[c + 1]), 0.f);
                v.z = fmaxf(fmaf(h.z, scl[c + 2], sft[c + 2]), 0.f);
                v.w = fmaxf(fmaf(h.w, scl[c + 3], sft[c + 3]), 0.f);
            }
            *(float4*)&lin[ln][q * 4] = v;
        }
    }
    __syncthreads();   // all reads of h1 rows done before overwrite

    const int r = t >> 2;
    const int g = t & 3;
    const int n = nbase + r;
    const float4* lW4 = (const float4*)lW;
    const float4* b4 = (const float4*)b2;
    float4 acc0 = b4[g * 4 + 0];
    float4 acc1 = b4[g * 4 + 1];
    float4 acc2 = b4[g * 4 + 2];
    float4 acc3 = b4[g * 4 + 3];
    for (int k = 0; k < 64; k++) {
        const float a = lin[r][k];
        const float4 w0 = lW4[k * 16 + g * 4 + 0];
        const float4 w1 = lW4[k * 16 + g * 4 + 1];
        const float4 w2 = lW4[k * 16 + g * 4 + 2];
        const float4 w3 = lW4[k * 16 + g * 4 + 3];
        acc0.x = fmaf(a, w0.x, acc0.x); acc0.y = fmaf(a, w0.y, acc0.y);
        acc0.z = fmaf(a, w0.z, acc0.z); acc0.w = fmaf(a, w0.w, acc0.w);
        acc1.x = fmaf(a, w1.x, acc1.x); acc1.y = fmaf(a, w1.y, acc1.y);
        acc1.z = fmaf(a, w1.z, acc1.z); acc1.w = fmaf(a, w1.w, acc1.w);
        acc2.x = fmaf(a, w2.x, acc2.x); acc2.y = fmaf(a, w2.y, acc2.y);
        acc2.z = fmaf(a, w2.z, acc2.z); acc2.w = fmaf(a, w2.w, acc2.w);
        acc3.x = fmaf(a, w3.x, acc3.x); acc3.y = fmaf(a, w3.y, acc3.y);
        acc3.z = fmaf(a, w3.z, acc3.z); acc3.w = fmaf(a, w3.w, acc3.w);
    }
    if (n < N_NODESC) {
        float4* o4 = (float4*)out;
        o4[(size_t)n * 16 + g * 4 + 0] = acc0;
        o4[(size_t)n * 16 + g * 4 + 1] = acc1;
        o4[(size_t)n * 16 + g * 4 + 2] = acc2;
        o4[(size_t)n * 16 + g * 4 + 3] = acc3;
    }
}

// ---------------------------------------------------------------------------
extern "C" void kernel_launch(void* const* d_in, const int* in_sizes, int n_in,
                              void* d_out, int out_size, void* d_ws, size_t ws_size,
                              hipStream_t stream) {
    const float* x     = (const float*)d_in[0];
    const float* emb   = (const float*)d_in[1];
    const float* eps   = (const float*)d_in[2];
    const float* W1    = (const float*)d_in[3];
    const float* b1    = (const float*)d_in[4];
    const float* gamma = (const float*)d_in[5];
    const float* beta  = (const float*)d_in[6];
    const float* W2    = (const float*)d_in[7];
    const float* b2    = (const float*)d_in[8];
    const int*   ei    = (const int*)d_in[9];
    const int*   ea    = (const int*)d_in[10];
    float* out = (float*)d_out;

    // workspace layout: [cs 64][css 64][agg N*64]  (h1 lives in d_out)
    float* ws  = (float*)d_ws;
    float* cs  = ws;
    float* css = ws + 64;
    float* agg = ws + 128;

    const size_t zero_bytes = (size_t)(128 + N_NODESC * 64) * sizeof(float);
    hipMemsetAsync(d_ws, 0, zero_bytes, stream);

    k_scatter<<<(N_EDGESC * 16) / 256, 256, 0, stream>>>(x, emb, ei, ea, agg);

    const int nblk = (N_NODESC + 63) / 64;
    k_mlp1<<<nblk, 256, 0, stream>>>(x, agg, W1, b1, eps, out, cs, css);
    k_mlp2<<<nblk, 256, 0, stream>>>(out, W2, b2, gamma, beta, cs, css, out);
}

// Round 2
// 673.247 us; speedup vs baseline: 2.2785x; 2.2785x over previous
//
#include <hip/hip_runtime.h>

#define N_NODESC 100000
#define N_EDGESC 1600000
#define BN_EPSC 1e-5f

// ---------------------------------------------------------------------------
// K_hist: deg[dst]++ per edge.  1.6M int atomics over a 400KB array.
// ---------------------------------------------------------------------------
__global__ __launch_bounds__(256) void k_hist(
    const int* __restrict__ ei, int* __restrict__ deg)
{
    const int e = blockIdx.x * 256 + threadIdx.x;
    atomicAdd(&deg[ei[N_EDGESC + e]], 1);
}

// ---------------------------------------------------------------------------
// K_scan: single-block exclusive scan of deg[0..N) -> off[0..N]; copy to
// cursor.  1024 threads, ~98 contiguous elements each, Hillis-Steele in LDS.
// ---------------------------------------------------------------------------
__global__ __launch_bounds__(1024) void k_scan(
    const int* __restrict__ deg, int* __restrict__ off, int* __restrict__ cursor)
{
    __shared__ int s[1024];
    const int t = threadIdx.x;
    const int CH = (N_NODESC + 1023) / 1024;   // 98
    const int base = t * CH;
    int sum = 0;
    for (int i = 0; i < CH; i++) {
        const int idx = base + i;
        if (idx < N_NODESC) sum += deg[idx];
    }
    s[t] = sum;
    __syncthreads();
    for (int d = 1; d < 1024; d <<= 1) {
        int v = (t >= d) ? s[t - d] : 0;
        __syncthreads();
        if (t >= d) s[t] += v;
        __syncthreads();
    }
    int run = (t == 0) ? 0 : s[t - 1];
    for (int i = 0; i < CH; i++) {
        const int idx = base + i;
        if (idx < N_NODESC) {
            off[idx] = run;
            cursor[idx] = run;
            run += deg[idx];
        }
    }
    if (t == 1023) off[N_NODESC] = s[1023];
}

// ---------------------------------------------------------------------------
// K_fill: place each edge into its dst bucket.  packed = src | (attr<<20).
// ---------------------------------------------------------------------------
__global__ __launch_bounds__(256) void k_fill(
    const int* __restrict__ ei, const int* __restrict__ ea,
    int* __restrict__ cursor, int* __restrict__ packed)
{
    const int e = blockIdx.x * 256 + threadIdx.x;
    const int src = ei[e];
    const int dst = ei[N_EDGESC + e];
    const int a = ea[e];
    const int pos = atomicAdd(&cursor[dst], 1);
    packed[pos] = src | (a << 20);
}

// ---------------------------------------------------------------------------
// K_agg: per-node register accumulation.  16 lanes per node (float4 each),
// 4 nodes per wave, 16 nodes per 256-thread block -> 6250 blocks exactly.
// agg written to d_out (overwritten row-aligned by k_mlp1 later).
// ---------------------------------------------------------------------------
__global__ __launch_bounds__(256) void k_agg(
    const float* __restrict__ x, const float* __restrict__ emb,
    const int* __restrict__ off, const int* __restrict__ packed,
    float* __restrict__ agg)
{
    const int t = threadIdx.x;
    const int q = t & 15;                       // float4 slot within row
    const int node = blockIdx.x * 16 + (t >> 4);
    const int start = off[node];
    const int end = off[node + 1];
    const float4* x4 = (const float4*)x;
    const float4* e4 = (const float4*)emb;
    float4 acc = make_float4(0.f, 0.f, 0.f, 0.f);
    for (int e = start; e < end; e++) {
        const int p = packed[e];
        const int src = p & 0xFFFFF;
        const int a = p >> 20;
        const float4 xv = x4[(size_t)src * 16 + q];
        const float4 tv = e4[a * 16 + q];
        acc.x += fmaxf(xv.x + tv.x, 0.f);
        acc.y += fmaxf(xv.y + tv.y, 0.f);
        acc.z += fmaxf(xv.z + tv.z, 0.f);
        acc.w += fmaxf(xv.w + tv.w, 0.f);
    }
    ((float4*)agg)[(size_t)node * 16 + q] = acc;
}

// ---------------------------------------------------------------------------
// K_mlp1: hbuf := ((1+eps)*x + hbuf) @ W1 + b1 ; accumulate BN column sums.
// hbuf holds agg on entry, h1 on exit (row-aligned, block-local staging).
// ---------------------------------------------------------------------------
__global__ __launch_bounds__(256) void k_mlp1(
    const float* __restrict__ x, float* hbuf,
    const float* __restrict__ W1, const float* __restrict__ b1,
    const float* __restrict__ epsp,
    float* __restrict__ cs, float* __restrict__ css)
{
    __shared__ float lin[64][68];   // +4 pad: 2-way bank alias only (free)
    __shared__ float lW[4096];
    __shared__ float redS[4][64];
    __shared__ float redQ[4][64];
    const int t = threadIdx.x;
    const int nbase = blockIdx.x * 64;
    const float sc1 = 1.0f + epsp[0];

    {   // stage W1 (64x64) into LDS, coalesced float4
        const float4* W4 = (const float4*)W1;
        float4* lW4 = (float4*)lW;
        #pragma unroll
        for (int i = 0; i < 4; i++) lW4[i * 256 + t] = W4[i * 256 + t];
    }
    {   // stage 64 input rows: (1+eps)*x + agg
        const float4* x4 = (const float4*)x;
        const float4* a4 = (const float4*)hbuf;
        #pragma unroll
        for (int i = 0; i < 4; i++) {
            const int ln = i * 16 + (t >> 4);
            const int q = t & 15;
            const int n = nbase + ln;
            float4 v = make_float4(0.f, 0.f, 0.f, 0.f);
            if (n < N_NODESC) {
                const float4 xv = x4[(size_t)n * 16 + q];
                const float4 av = a4[(size_t)n * 16 + q];
                v.x = fmaf(sc1, xv.x, av.x);
                v.y = fmaf(sc1, xv.y, av.y);
                v.z = fmaf(sc1, xv.z, av.z);
                v.w = fmaf(sc1, xv.w, av.w);
            }
            *(float4*)&lin[ln][q * 4] = v;
        }
    }
    __syncthreads();   // all agg reads done before h1 overwrite below

    const int r = t >> 2;
    const int g = t & 3;
    const int n = nbase + r;
    const float4* lW4 = (const float4*)lW;
    const float4* b4 = (const float4*)b1;
    float4 acc0 = b4[g * 4 + 0];
    float4 acc1 = b4[g * 4 + 1];
    float4 acc2 = b4[g * 4 + 2];
    float4 acc3 = b4[g * 4 + 3];
    for (int k = 0; k < 64; k++) {
        const float a = lin[r][k];
        const float4 w0 = lW4[k * 16 + g * 4 + 0];
        const float4 w1 = lW4[k * 16 + g * 4 + 1];
        const float4 w2 = lW4[k * 16 + g * 4 + 2];
        const float4 w3 = lW4[k * 16 + g * 4 + 3];
        acc0.x = fmaf(a, w0.x, acc0.x); acc0.y = fmaf(a, w0.y, acc0.y);
        acc0.z = fmaf(a, w0.z, acc0.z); acc0.w = fmaf(a, w0.w, acc0.w);
        acc1.x = fmaf(a, w1.x, acc1.x); acc1.y = fmaf(a, w1.y, acc1.y);
        acc1.z = fmaf(a, w1.z, acc1.z); acc1.w = fmaf(a, w1.w, acc1.w);
        acc2.x = fmaf(a, w2.x, acc2.x); acc2.y = fmaf(a, w2.y, acc2.y);
        acc2.z = fmaf(a, w2.z, acc2.z); acc2.w = fmaf(a, w2.w, acc2.w);
        acc3.x = fmaf(a, w3.x, acc3.x); acc3.y = fmaf(a, w3.y, acc3.y);
        acc3.z = fmaf(a, w3.z, acc3.z); acc3.w = fmaf(a, w3.w, acc3.w);
    }
    if (n < N_NODESC) {
        float4* h4 = (float4*)hbuf;
        h4[(size_t)n * 16 + g * 4 + 0] = acc0;
        h4[(size_t)n * 16 + g * 4 + 1] = acc1;
        h4[(size_t)n * 16 + g * 4 + 2] = acc2;
        h4[(size_t)n * 16 + g * 4 + 3] = acc3;
    }

    // --- BN partial stats: reduce over the 16 rows in each wave via shfl ---
    float vs[16], vq[16];
    const float msk = (n < N_NODESC) ? 1.0f : 0.0f;
    {
        const float a0[16] = {acc0.x, acc0.y, acc0.z, acc0.w,
                              acc1.x, acc1.y, acc1.z, acc1.w,
                              acc2.x, acc2.y, acc2.z, acc2.w,
                              acc3.x, acc3.y, acc3.z, acc3.w};
        #pragma unroll
        for (int i = 0; i < 16; i++) {
            const float v = a0[i] * msk;
            vs[i] = v;
            vq[i] = v * a0[i];
        }
    }
    #pragma unroll
    for (int off2 = 4; off2 < 64; off2 <<= 1) {
        #pragma unroll
        for (int i = 0; i < 16; i++) {
            vs[i] += __shfl_xor(vs[i], off2);
            vq[i] += __shfl_xor(vq[i], off2);
        }
    }
    const int lane = t & 63;
    const int w = t >> 6;
    if (lane < 4) {
        #pragma unroll
        for (int i = 0; i < 16; i++) {
            redS[w][lane * 16 + i] = vs[i];
            redQ[w][lane * 16 + i] = vq[i];
        }
    }
    __syncthreads();
    if (t < 64) {
        const float s = redS[0][t] + redS[1][t] + redS[2][t] + redS[3][t];
        const float qq = redQ[0][t] + redQ[1][t] + redQ[2][t] + redQ[3][t];
        unsafeAtomicAdd(&cs[t], s);
        unsafeAtomicAdd(&css[t], qq);
    }
}

// ---------------------------------------------------------------------------
// K_mlp2: out = relu(BN(h1)) @ W2 + b2.  h1 aliases out (d_out); each block
// stages its 64 rows into LDS (barrier) before overwriting them.
// ---------------------------------------------------------------------------
__global__ __launch_bounds__(256) void k_mlp2(
    const float* h1, const float* __restrict__ W2, const float* __restrict__ b2,
    const float* __restrict__ gamma, const float* __restrict__ beta,
    const float* __restrict__ cs, const float* __restrict__ css,
    float* out)
{
    __shared__ float lin[64][68];
    __shared__ float lW[4096];
    __shared__ float scl[64];
    __shared__ float sft[64];
    const int t = threadIdx.x;
    const int nbase = blockIdx.x * 64;

    if (t < 64) {
        const float inv = 1.0f / (float)N_NODESC;
        const float mu = cs[t] * inv;
        const float var = css[t] * inv - mu * mu;
        const float rs = rsqrtf(var + BN_EPSC);
        const float s = rs * gamma[t];
        scl[t] = s;
        sft[t] = fmaf(-mu, s, beta[t]);
    }
    {
        const float4* W4 = (const float4*)W2;
        float4* lW4 = (float4*)lW;
        #pragma unroll
        for (int i = 0; i < 4; i++) lW4[i * 256 + t] = W4[i * 256 + t];
    }
    __syncthreads();   // scl/sft ready
    {
        const float4* h4 = (const float4*)h1;
        #pragma unroll
        for (int i = 0; i < 4; i++) {
            const int ln = i * 16 + (t >> 4);
            const int q = t & 15;
            const int n = nbase + ln;
            float4 v = make_float4(0.f, 0.f, 0.f, 0.f);
            if (n < N_NODESC) {
                const float4 h = h4[(size_t)n * 16 + q];
                const int c = q * 4;
                v.x = fmaxf(fmaf(h.x, scl[c + 0], sft[c + 0]), 0.f);
                v.y = fmaxf(fmaf(h.y, scl[c + 1], sft[c + 1]), 0.f);
                v.z = fmaxf(fmaf(h.z, scl[c + 2], sft[c + 2]), 0.f);
                v.w = fmaxf(fmaf(h.w, scl[c + 3], sft[c + 3]), 0.f);
            }
            *(float4*)&lin[ln][q * 4] = v;
        }
    }
    __syncthreads();   // all reads of h1 rows done before overwrite

    const int r = t >> 2;
    const int g = t & 3;
    const int n = nbase + r;
    const float4* lW4 = (const float4*)lW;
    const float4* b4 = (const float4*)b2;
    float4 acc0 = b4[g * 4 + 0];
    float4 acc1 = b4[g * 4 + 1];
    float4 acc2 = b4[g * 4 + 2];
    float4 acc3 = b4[g * 4 + 3];
    for (int k = 0; k < 64; k++) {
        const float a = lin[r][k];
        const float4 w0 = lW4[k * 16 + g * 4 + 0];
        const float4 w1 = lW4[k * 16 + g * 4 + 1];
        const float4 w2 = lW4[k * 16 + g * 4 + 2];
        const float4 w3 = lW4[k * 16 + g * 4 + 3];
        acc0.x = fmaf(a, w0.x, acc0.x); acc0.y = fmaf(a, w0.y, acc0.y);
        acc0.z = fmaf(a, w0.z, acc0.z); acc0.w = fmaf(a, w0.w, acc0.w);
        acc1.x = fmaf(a, w1.x, acc1.x); acc1.y = fmaf(a, w1.y, acc1.y);
        acc1.z = fmaf(a, w1.z, acc1.z); acc1.w = fmaf(a, w1.w, acc1.w);
        acc2.x = fmaf(a, w2.x, acc2.x); acc2.y = fmaf(a, w2.y, acc2.y);
        acc2.z = fmaf(a, w2.z, acc2.z); acc2.w = fmaf(a, w2.w, acc2.w);
        acc3.x = fmaf(a, w3.x, acc3.x); acc3.y = fmaf(a, w3.y, acc3.y);
        acc3.z = fmaf(a, w3.z, acc3.z); acc3.w = fmaf(a, w3.w, acc3.w);
    }
    if (n < N_NODESC) {
        float4* o4 = (float4*)out;
        o4[(size_t)n * 16 + g * 4 + 0] = acc0;
        o4[(size_t)n * 16 + g * 4 + 1] = acc1;
        o4[(size_t)n * 16 + g * 4 + 2] = acc2;
        o4[(size_t)n * 16 + g * 4 + 3] = acc3;
    }
}

// ---------------------------------------------------------------------------
extern "C" void kernel_launch(void* const* d_in, const int* in_sizes, int n_in,
                              void* d_out, int out_size, void* d_ws, size_t ws_size,
                              hipStream_t stream) {
    const float* x     = (const float*)d_in[0];
    const float* emb   = (const float*)d_in[1];
    const float* eps   = (const float*)d_in[2];
    const float* W1    = (const float*)d_in[3];
    const float* b1    = (const float*)d_in[4];
    const float* gamma = (const float*)d_in[5];
    const float* beta  = (const float*)d_in[6];
    const float* W2    = (const float*)d_in[7];
    const float* b2    = (const float*)d_in[8];
    const int*   ei    = (const int*)d_in[9];
    const int*   ea    = (const int*)d_in[10];
    float* out = (float*)d_out;

    // workspace: [cs 64][css 64][deg 100000][off 100001][cursor 100000][packed 1.6M]
    float* ws    = (float*)d_ws;
    float* cs    = ws;
    float* css   = ws + 64;
    int*   deg   = (int*)(ws + 128);
    int*   off   = deg + N_NODESC;
    int*   cur   = off + N_NODESC + 1;
    int*   packed= cur + N_NODESC;

    // zero cs/css/deg only (off/cursor/packed are fully written)
    hipMemsetAsync(d_ws, 0, (size_t)(128 + N_NODESC) * sizeof(float), stream);

    const int eblk = N_EDGESC / 256;            // 6250 exactly
    k_hist<<<eblk, 256, 0, stream>>>(ei, deg);
    k_scan<<<1, 1024, 0, stream>>>(deg, off, cur);
    k_fill<<<eblk, 256, 0, stream>>>(ei, ea, cur, packed);
    k_agg<<<N_NODESC / 16, 256, 0, stream>>>(x, emb, off, packed, out);  // agg -> d_out

    const int nblk = (N_NODESC + 63) / 64;
    k_mlp1<<<nblk, 256, 0, stream>>>(x, out, W1, b1, eps, cs, css);      // agg -> h1 in d_out
    k_mlp2<<<nblk, 256, 0, stream>>>(out, W2, b2, gamma, beta, cs, css, out);
}

// Round 3
// 434.183 us; speedup vs baseline: 3.5331x; 1.5506x over previous
//
#include <hip/hip_runtime.h>

#define N_NODESC 100000
#define N_EDGESC 1600000
#define BN_EPSC 1e-5f
#define SCAN_BLKS 391   // ceil(100000/256)

// ---------------------------------------------------------------------------
// K_hist: deg[dst]++ per edge.  1.6M int atomics over a 400KB array.
// ---------------------------------------------------------------------------
__global__ __launch_bounds__(256) void k_hist(
    const int* __restrict__ ei, int* __restrict__ deg)
{
    const int e = blockIdx.x * 256 + threadIdx.x;
    atomicAdd(&deg[ei[N_EDGESC + e]], 1);
}

// ---------------------------------------------------------------------------
// K_scan1: per-block exclusive scan (256 elems/block) + block totals.
// ---------------------------------------------------------------------------
__global__ __launch_bounds__(256) void k_scan1(
    const int* __restrict__ deg, int* __restrict__ local, int* __restrict__ bsum)
{
    __shared__ int wsum[4];
    const int t = threadIdx.x;
    const int i = blockIdx.x * 256 + t;
    const int lane = t & 63;
    const int wid = t >> 6;
    const int v = (i < N_NODESC) ? deg[i] : 0;
    int inc = v;
    #pragma unroll
    for (int d = 1; d < 64; d <<= 1) {
        const int u = __shfl_up(inc, d);
        if (lane >= d) inc += u;
    }
    if (lane == 63) wsum[wid] = inc;
    __syncthreads();
    int add = 0;
    #pragma unroll
    for (int w = 0; w < 3; w++) if (w < wid) add += wsum[w];
    local[i] = inc - v + add;                    // exclusive within block
    if (t == 255) bsum[blockIdx.x] = add + inc;  // block total
}

// ---------------------------------------------------------------------------
// K_scan2: scan the 391 block totals (one small block), write grand total.
// ---------------------------------------------------------------------------
__global__ __launch_bounds__(512) void k_scan2(
    const int* __restrict__ bsum, int* __restrict__ bsumx, int* __restrict__ off)
{
    __shared__ int s[512];
    const int t = threadIdx.x;
    const int v = (t < SCAN_BLKS) ? bsum[t] : 0;
    s[t] = v;
    __syncthreads();
    for (int d = 1; d < 512; d <<= 1) {
        const int u = (t >= d) ? s[t - d] : 0;
        __syncthreads();
        s[t] += u;
        __syncthreads();
    }
    if (t < SCAN_BLKS) bsumx[t] = s[t] - v;      // exclusive
    if (t == SCAN_BLKS - 1) off[N_NODESC] = s[t];
}

// ---------------------------------------------------------------------------
// K_scan3: off[i] = cursor[i] = local[i] + bsumx[block].
// ---------------------------------------------------------------------------
__global__ __launch_bounds__(256) void k_scan3(
    const int* __restrict__ local, const int* __restrict__ bsumx,
    int* __restrict__ off, int* __restrict__ cur)
{
    const int i = blockIdx.x * 256 + threadIdx.x;
    if (i < N_NODESC) {
        const int v = local[i] + bsumx[blockIdx.x];
        off[i] = v;
        cur[i] = v;
    }
}

// ---------------------------------------------------------------------------
// K_fill: place each edge into its dst bucket.  packed = src | (attr<<20).
// ---------------------------------------------------------------------------
__global__ __launch_bounds__(256) void k_fill(
    const int* __restrict__ ei, const int* __restrict__ ea,
    int* __restrict__ cursor, int* __restrict__ packed)
{
    const int e = blockIdx.x * 256 + threadIdx.x;
    const int src = ei[e];
    const int dst = ei[N_EDGESC + e];
    const int a = ea[e];
    const int pos = atomicAdd(&cursor[dst], 1);
    packed[pos] = src | (a << 20);
}

// ---------------------------------------------------------------------------
// K_agg: per-node register accumulation.  16 lanes per node (float4 each),
// 4 nodes per wave, 16 nodes per 256-thread block -> 6250 blocks exactly.
// agg written to d_out (overwritten row-aligned by k_mlp1 later).
// ---------------------------------------------------------------------------
__global__ __launch_bounds__(256) void k_agg(
    const float* __restrict__ x, const float* __restrict__ emb,
    const int* __restrict__ off, const int* __restrict__ packed,
    float* __restrict__ agg)
{
    const int t = threadIdx.x;
    const int q = t & 15;                       // float4 slot within row
    const int node = blockIdx.x * 16 + (t >> 4);
    const int start = off[node];
    const int end = off[node + 1];
    const float4* x4 = (const float4*)x;
    const float4* e4 = (const float4*)emb;
    float4 acc = make_float4(0.f, 0.f, 0.f, 0.f);
    for (int e = start; e < end; e++) {
        const int p = packed[e];
        const int src = p & 0xFFFFF;
        const int a = p >> 20;
        const float4 xv = x4[(size_t)src * 16 + q];
        const float4 tv = e4[a * 16 + q];
        acc.x += fmaxf(xv.x + tv.x, 0.f);
        acc.y += fmaxf(xv.y + tv.y, 0.f);
        acc.z += fmaxf(xv.z + tv.z, 0.f);
        acc.w += fmaxf(xv.w + tv.w, 0.f);
    }
    ((float4*)agg)[(size_t)node * 16 + q] = acc;
}

// ---------------------------------------------------------------------------
// K_mlp1: hbuf := ((1+eps)*x + hbuf) @ W1 + b1 ; accumulate BN column sums.
// hbuf holds agg on entry, h1 on exit (row-aligned, block-local staging).
// ---------------------------------------------------------------------------
__global__ __launch_bounds__(256) void k_mlp1(
    const float* __restrict__ x, float* hbuf,
    const float* __restrict__ W1, const float* __restrict__ b1,
    const float* __restrict__ epsp,
    float* __restrict__ cs, float* __restrict__ css)
{
    __shared__ float lin[64][68];   // +4 pad: 2-way bank alias only (free)
    __shared__ float lW[4096];
    __shared__ float redS[4][64];
    __shared__ float redQ[4][64];
    const int t = threadIdx.x;
    const int nbase = blockIdx.x * 64;
    const float sc1 = 1.0f + epsp[0];

    {   // stage W1 (64x64) into LDS, coalesced float4
        const float4* W4 = (const float4*)W1;
        float4* lW4 = (float4*)lW;
        #pragma unroll
        for (int i = 0; i < 4; i++) lW4[i * 256 + t] = W4[i * 256 + t];
    }
    {   // stage 64 input rows: (1+eps)*x + agg
        const float4* x4 = (const float4*)x;
        const float4* a4 = (const float4*)hbuf;
        #pragma unroll
        for (int i = 0; i < 4; i++) {
            const int ln = i * 16 + (t >> 4);
            const int q = t & 15;
            const int n = nbase + ln;
            float4 v = make_float4(0.f, 0.f, 0.f, 0.f);
            if (n < N_NODESC) {
                const float4 xv = x4[(size_t)n * 16 + q];
                const float4 av = a4[(size_t)n * 16 + q];
                v.x = fmaf(sc1, xv.x, av.x);
                v.y = fmaf(sc1, xv.y, av.y);
                v.z = fmaf(sc1, xv.z, av.z);
                v.w = fmaf(sc1, xv.w, av.w);
            }
            *(float4*)&lin[ln][q * 4] = v;
        }
    }
    __syncthreads();   // all agg reads done before h1 overwrite below

    const int r = t >> 2;
    const int g = t & 3;
    const int n = nbase + r;
    const float4* lW4 = (const float4*)lW;
    const float4* b4 = (const float4*)b1;
    float4 acc0 = b4[g * 4 + 0];
    float4 acc1 = b4[g * 4 + 1];
    float4 acc2 = b4[g * 4 + 2];
    float4 acc3 = b4[g * 4 + 3];
    for (int k = 0; k < 64; k++) {
        const float a = lin[r][k];
        const float4 w0 = lW4[k * 16 + g * 4 + 0];
        const float4 w1 = lW4[k * 16 + g * 4 + 1];
        const float4 w2 = lW4[k * 16 + g * 4 + 2];
        const float4 w3 = lW4[k * 16 + g * 4 + 3];
        acc0.x = fmaf(a, w0.x, acc0.x); acc0.y = fmaf(a, w0.y, acc0.y);
        acc0.z = fmaf(a, w0.z, acc0.z); acc0.w = fmaf(a, w0.w, acc0.w);
        acc1.x = fmaf(a, w1.x, acc1.x); acc1.y = fmaf(a, w1.y, acc1.y);
        acc1.z = fmaf(a, w1.z, acc1.z); acc1.w = fmaf(a, w1.w, acc1.w);
        acc2.x = fmaf(a, w2.x, acc2.x); acc2.y = fmaf(a, w2.y, acc2.y);
        acc2.z = fmaf(a, w2.z, acc2.z); acc2.w = fmaf(a, w2.w, acc2.w);
        acc3.x = fmaf(a, w3.x, acc3.x); acc3.y = fmaf(a, w3.y, acc3.y);
        acc3.z = fmaf(a, w3.z, acc3.z); acc3.w = fmaf(a, w3.w, acc3.w);
    }
    if (n < N_NODESC) {
        float4* h4 = (float4*)hbuf;
        h4[(size_t)n * 16 + g * 4 + 0] = acc0;
        h4[(size_t)n * 16 + g * 4 + 1] = acc1;
        h4[(size_t)n * 16 + g * 4 + 2] = acc2;
        h4[(size_t)n * 16 + g * 4 + 3] = acc3;
    }

    // --- BN partial stats: reduce over the 16 rows in each wave via shfl ---
    float vs[16], vq[16];
    const float msk = (n < N_NODESC) ? 1.0f : 0.0f;
    {
        const float a0[16] = {acc0.x, acc0.y, acc0.z, acc0.w,
                              acc1.x, acc1.y, acc1.z, acc1.w,
                              acc2.x, acc2.y, acc2.z, acc2.w,
                              acc3.x, acc3.y, acc3.z, acc3.w};
        #pragma unroll
        for (int i = 0; i < 16; i++) {
            const float v = a0[i] * msk;
            vs[i] = v;
            vq[i] = v * a0[i];
        }
    }
    #pragma unroll
    for (int off2 = 4; off2 < 64; off2 <<= 1) {
        #pragma unroll
        for (int i = 0; i < 16; i++) {
            vs[i] += __shfl_xor(vs[i], off2);
            vq[i] += __shfl_xor(vq[i], off2);
        }
    }
    const int lane = t & 63;
    const int w = t >> 6;
    if (lane < 4) {
        #pragma unroll
        for (int i = 0; i < 16; i++) {
            redS[w][lane * 16 + i] = vs[i];
            redQ[w][lane * 16 + i] = vq[i];
        }
    }
    __syncthreads();
    if (t < 64) {
        const float s = redS[0][t] + redS[1][t] + redS[2][t] + redS[3][t];
        const float qq = redQ[0][t] + redQ[1][t] + redQ[2][t] + redQ[3][t];
        unsafeAtomicAdd(&cs[t], s);
        unsafeAtomicAdd(&css[t], qq);
    }
}

// ---------------------------------------------------------------------------
// K_mlp2: out = relu(BN(h1)) @ W2 + b2.  h1 aliases out (d_out); each block
// stages its 64 rows into LDS (barrier) before overwriting them.
// ---------------------------------------------------------------------------
__global__ __launch_bounds__(256) void k_mlp2(
    const float* h1, const float* __restrict__ W2, const float* __restrict__ b2,
    const float* __restrict__ gamma, const float* __restrict__ beta,
    const float* __restrict__ cs, const float* __restrict__ css,
    float* out)
{
    __shared__ float lin[64][68];
    __shared__ float lW[4096];
    __shared__ float scl[64];
    __shared__ float sft[64];
    const int t = threadIdx.x;
    const int nbase = blockIdx.x * 64;

    if (t < 64) {
        const float inv = 1.0f / (float)N_NODESC;
        const float mu = cs[t] * inv;
        const float var = css[t] * inv - mu * mu;
        const float rs = rsqrtf(var + BN_EPSC);
        const float s = rs * gamma[t];
        scl[t] = s;
        sft[t] = fmaf(-mu, s, beta[t]);
    }
    {
        const float4* W4 = (const float4*)W2;
        float4* lW4 = (float4*)lW;
        #pragma unroll
        for (int i = 0; i < 4; i++) lW4[i * 256 + t] = W4[i * 256 + t];
    }
    __syncthreads();   // scl/sft ready
    {
        const float4* h4 = (const float4*)h1;
        #pragma unroll
        for (int i = 0; i < 4; i++) {
            const int ln = i * 16 + (t >> 4);
            const int q = t & 15;
            const int n = nbase + ln;
            float4 v = make_float4(0.f, 0.f, 0.f, 0.f);
            if (n < N_NODESC) {
                const float4 h = h4[(size_t)n * 16 + q];
                const int c = q * 4;
                v.x = fmaxf(fmaf(h.x, scl[c + 0], sft[c + 0]), 0.f);
                v.y = fmaxf(fmaf(h.y, scl[c + 1], sft[c + 1]), 0.f);
                v.z = fmaxf(fmaf(h.z, scl[c + 2], sft[c + 2]), 0.f);
                v.w = fmaxf(fmaf(h.w, scl[c + 3], sft[c + 3]), 0.f);
            }
            *(float4*)&lin[ln][q * 4] = v;
        }
    }
    __syncthreads();   // all reads of h1 rows done before overwrite

    const int r = t >> 2;
    const int g = t & 3;
    const int n = nbase + r;
    const float4* lW4 = (const float4*)lW;
    const float4* b4 = (const float4*)b2;
    float4 acc0 = b4[g * 4 + 0];
    float4 acc1 = b4[g * 4 + 1];
    float4 acc2 = b4[g * 4 + 2];
    float4 acc3 = b4[g * 4 + 3];
    for (int k = 0; k < 64; k++) {
        const float a = lin[r][k];
        const float4 w0 = lW4[k * 16 + g * 4 + 0];
        const float4 w1 = lW4[k * 16 + g * 4 + 1];
        const float4 w2 = lW4[k * 16 + g * 4 + 2];
        const float4 w3 = lW4[k * 16 + g * 4 + 3];
        acc0.x = fmaf(a, w0.x, acc0.x); acc0.y = fmaf(a, w0.y, acc0.y);
        acc0.z = fmaf(a, w0.z, acc0.z); acc0.w = fmaf(a, w0.w, acc0.w);
        acc1.x = fmaf(a, w1.x, acc1.x); acc1.y = fmaf(a, w1.y, acc1.y);
        acc1.z = fmaf(a, w1.z, acc1.z); acc1.w = fmaf(a, w1.w, acc1.w);
        acc2.x = fmaf(a, w2.x, acc2.x); acc2.y = fmaf(a, w2.y, acc2.y);
        acc2.z = fmaf(a, w2.z, acc2.z); acc2.w = fmaf(a, w2.w, acc2.w);
        acc3.x = fmaf(a, w3.x, acc3.x); acc3.y = fmaf(a, w3.y, acc3.y);
        acc3.z = fmaf(a, w3.z, acc3.z); acc3.w = fmaf(a, w3.w, acc3.w);
    }
    if (n < N_NODESC) {
        float4* o4 = (float4*)out;
        o4[(size_t)n * 16 + g * 4 + 0] = acc0;
        o4[(size_t)n * 16 + g * 4 + 1] = acc1;
        o4[(size_t)n * 16 + g * 4 + 2] = acc2;
        o4[(size_t)n * 16 + g * 4 + 3] = acc3;
    }
}

// ---------------------------------------------------------------------------
extern "C" void kernel_launch(void* const* d_in, const int* in_sizes, int n_in,
                              void* d_out, int out_size, void* d_ws, size_t ws_size,
                              hipStream_t stream) {
    const float* x     = (const float*)d_in[0];
    const float* emb   = (const float*)d_in[1];
    const float* eps   = (const float*)d_in[2];
    const float* W1    = (const float*)d_in[3];
    const float* b1    = (const float*)d_in[4];
    const float* gamma = (const float*)d_in[5];
    const float* beta  = (const float*)d_in[6];
    const float* W2    = (const float*)d_in[7];
    const float* b2    = (const float*)d_in[8];
    const int*   ei    = (const int*)d_in[9];
    const int*   ea    = (const int*)d_in[10];
    float* out = (float*)d_out;

    // workspace: [cs 64][css 64][deg N][off N+1][cur N][local 391*256]
    //            [bsum 391][bsumx 391][pad][packed E]
    float* ws    = (float*)d_ws;
    float* cs    = ws;
    float* css   = ws + 64;
    int*   deg   = (int*)(ws + 128);
    int*   off   = deg + N_NODESC;
    int*   cur   = off + N_NODESC + 1;
    int*   local = cur + N_NODESC;
    int*   bsum  = local + SCAN_BLKS * 256;
    int*   bsumx = bsum + SCAN_BLKS;
    int*   packed= bsumx + SCAN_BLKS + 27;   // keep packed 64B-aligned

    // zero cs/css/deg only (everything else is fully written)
    hipMemsetAsync(d_ws, 0, (size_t)(128 + N_NODESC) * sizeof(float), stream);

    const int eblk = N_EDGESC / 256;            // 6250 exactly
    k_hist<<<eblk, 256, 0, stream>>>(ei, deg);
    k_scan1<<<SCAN_BLKS, 256, 0, stream>>>(deg, local, bsum);
    k_scan2<<<1, 512, 0, stream>>>(bsum, bsumx, off);
    k_scan3<<<SCAN_BLKS, 256, 0, stream>>>(local, bsumx, off, cur);
    k_fill<<<eblk, 256, 0, stream>>>(ei, ea, cur, packed);
    k_agg<<<N_NODESC / 16, 256, 0, stream>>>(x, emb, off, packed, out);  // agg -> d_out

    const int nblk = (N_NODESC + 63) / 64;
    k_mlp1<<<nblk, 256, 0, stream>>>(x, out, W1, b1, eps, cs, css);      // agg -> h1 in d_out
    k_mlp2<<<nblk, 256, 0, stream>>>(out, W2, b2, gamma, beta, cs, css, out);
}